// Round 5
// baseline (6558.410 us; speedup 1.0000x reference)
//
#include <hip/hip_runtime.h>
#include <stdint.h>
#include <stddef.h>

#define T_LEN 1024
#define BATCH 64
#define KDIM  256
#define HID   256
#define NGATE 5
#define GROWS (NGATE * HID)   // 1280
#define NGT   (GROWS / 16)    // 80 gate tiles of 16 rows
#define NSWG  4               // scan WGs: 16 batch rows each, fully independent

typedef __attribute__((ext_vector_type(8))) short s16x8;   // 8 bf16
typedef __attribute__((ext_vector_type(4))) float f32x4;
typedef __attribute__((ext_vector_type(4))) int   i32x4;
typedef __attribute__((ext_vector_type(2))) unsigned int u32x2;

static __device__ __forceinline__ uint16_t f2bf(float f) {
  uint32_t u = __float_as_uint(f);
  return (uint16_t)((u + 0x7fffu + ((u >> 16) & 1u)) >> 16);   // RNE
}
static __device__ __forceinline__ float bf2f(uint16_t b) {
  return __uint_as_float(((uint32_t)b) << 16);
}
static __device__ __forceinline__ s16x8 cvt8(const float* __restrict__ p) {
  float4 a = *reinterpret_cast<const float4*>(p);
  float4 b = *reinterpret_cast<const float4*>(p + 4);
  union { s16x8 v; uint16_t u[8]; } r;
  r.u[0] = f2bf(a.x); r.u[1] = f2bf(a.y); r.u[2] = f2bf(a.z); r.u[3] = f2bf(a.w);
  r.u[4] = f2bf(b.x); r.u[5] = f2bf(b.y); r.u[6] = f2bf(b.z); r.u[7] = f2bf(b.w);
  return r.v;
}
static __device__ __forceinline__ float sigm(float x)   { return 1.f / (1.f + __expf(-x)); }
static __device__ __forceinline__ float tanh_f(float x) { return 1.f - 2.f / (__expf(2.f * x) + 1.f); }
// LDS swizzle: XOR 16B-block index with row (breaks the stride-256B bank collision)
static __device__ __forceinline__ int swz(int row, int col) {
  return ((((col >> 4) ^ (row & 15)) << 4) | (col & 15));
}

// ---------------- setup: W_ih -> bf16, c0 -> cbuf ----------------
__global__ void setup_kernel(const float* __restrict__ Wih, const float* __restrict__ c0,
                             uint16_t* __restrict__ wihb, float* __restrict__ cbuf) {
  int i = blockIdx.x * 256 + threadIdx.x;
  if (i < GROWS * KDIM) wihb[i] = f2bf(Wih[i]);
  if (i < BATCH * HID) cbuf[i] = c0[i];
}

// ---------------- W_hh -> int8 per-row quant ----------------
__global__ void wquant_kernel(const float* __restrict__ Whh,
                              int8_t* __restrict__ wq, float* __restrict__ wsc) {
  int row = blockIdx.x * 256 + threadIdx.x;
  if (row >= GROWS) return;
  const float* wr = Whh + (size_t)row * KDIM;
  float mx = 1e-30f;
  for (int k = 0; k < KDIM; ++k) mx = fmaxf(mx, fabsf(wr[k]));
  wsc[row] = mx / 127.f;
  const float inv = 127.f / mx;
  int8_t* q = wq + (size_t)row * KDIM;
  for (int k = 0; k < KDIM; ++k) q[k] = (int8_t)__float2int_rn(wr[k] * inv);
}

// ---------------- x projection (bf16 MFMA, per-lane C-fragment layout) ----------------
__global__ __launch_bounds__(256, 2)
void xproj_kernel(const float* __restrict__ x, const uint16_t* __restrict__ wihb,
                  const float* __restrict__ bias, uint16_t* __restrict__ xp, int t0) {
  const int w = threadIdx.x >> 6, lane = threadIdx.x & 63;
  const int r16 = lane & 15, ke = (lane >> 4) * 8;
  const int tA = t0 + (int)blockIdx.x * 2;

  s16x8 A[2][8];
#pragma unroll
  for (int tt = 0; tt < 2; ++tt) {
    const float* ap = x + ((size_t)(tA + tt) * BATCH + w * 16 + r16) * KDIM + ke;
#pragma unroll
    for (int ks = 0; ks < 8; ++ks) A[tt][ks] = cvt8(ap + ks * 32);
  }
  for (int gt = 0; gt < NGT; ++gt) {
    const uint16_t* bp = wihb + (size_t)(gt * 16 + r16) * KDIM + ke;
    s16x8 B[8];
#pragma unroll
    for (int ks = 0; ks < 8; ++ks) B[ks] = *reinterpret_cast<const s16x8*>(bp + ks * 32);
    const float bv = bias[gt * 16 + r16];
#pragma unroll
    for (int tt = 0; tt < 2; ++tt) {
      f32x4 acc = {};
#pragma unroll
      for (int ks = 0; ks < 8; ++ks)
        acc = __builtin_amdgcn_mfma_f32_16x16x32_bf16(A[tt][ks], B[ks], acc, 0, 0, 0);
      const int lt = (int)blockIdx.x * 2 + tt;
      uint32_t w0 = (uint32_t)f2bf(acc[0] + bv) | ((uint32_t)f2bf(acc[1] + bv) << 16);
      uint32_t w1 = (uint32_t)f2bf(acc[2] + bv) | ((uint32_t)f2bf(acc[3] + bv) << 16);
      u32x2 pk = {w0, w1};
      u32x2* dst = (u32x2*)((uint32_t*)(xp + ((size_t)(lt * 4 + w) * NGT + gt) * 256) + lane * 2);
      __builtin_nontemporal_store(pk, dst);
    }
  }
}

// ---------------- sequential scan: 4 independent WGs, zero inter-WG traffic ----------------
// WG owns 16 batch rows; 8 waves; wave v owns H-cols [v*16,v*16+16) and [128+v*16,...).
// All of W_hh resident as i8 fragments (160 VGPR/lane). h exchanged via LDS (i8,
// double-buffered, XOR-swizzled) + one __syncthreads per step. c in registers.
__global__ __launch_bounds__(512, 2)
void scan_kernel(const float* __restrict__ mIn, const int8_t* __restrict__ wq,
                 const float* __restrict__ wsc, const uint16_t* __restrict__ xp,
                 const float* __restrict__ h_src, float* __restrict__ cbuf,
                 float* __restrict__ seq, float* __restrict__ hT, float* __restrict__ cT,
                 int s0, int s1) {
  __shared__ int8_t hq[2][16][256];   // 8 KB double buffer
  const int wg = blockIdx.x;                // batch tile (16 rows)
  const int v = threadIdx.x >> 6;           // wave 0..7
  const int lane = threadIdx.x & 63;
  const int r16 = lane & 15, g4 = lane >> 4;
  const int bj0 = g4 * 4;                   // batch row (within tile) base, C layout
  const int brow = wg * 16;                 // global batch base

  // Resident W_hh i8 fragments + scales: [half][gate][kstep]
  i32x4 Wf[2][NGATE][4];
  float sc[2][NGATE];
#pragma unroll
  for (int h2 = 0; h2 < 2; ++h2)
#pragma unroll
    for (int g = 0; g < NGATE; ++g) {
      const int grow = g * 256 + (v + 8 * h2) * 16 + r16;
      const int8_t* wp = wq + (size_t)grow * KDIM + g4 * 16;
#pragma unroll
      for (int ks = 0; ks < 4; ++ks)
        Wf[h2][g][ks] = *reinterpret_cast<const i32x4*>(wp + ks * 64);
      sc[h2][g] = wsc[grow] * (1.f / 127.f);
    }

  float c[2][4];
#pragma unroll
  for (int h2 = 0; h2 < 2; ++h2)
#pragma unroll
    for (int j = 0; j < 4; ++j)
      c[h2][j] = cbuf[(size_t)(brow + bj0 + j) * HID + h2 * 128 + v * 16 + r16];

  // cooperative: quantize entry h (h0 or seq[s0-1]) into LDS buf parity s0&1
  {
    const int p0 = s0 & 1;
    for (int e = 0; e < 8; ++e) {
      int t = (int)threadIdx.x * 8 + e;
      int row = t >> 8, col = t & 255;
      float hv = h_src[(size_t)(brow + row) * HID + col];
      int q = __float2int_rn(fminf(fmaxf(hv * 127.f, -127.f), 127.f));
      hq[p0][row][swz(row, col)] = (int8_t)q;
    }
  }
  __syncthreads();

  for (int s = s0; s < s1; ++s) {
    const int lt = s - s0, p = s & 1;
    // prefetch xp + m (HBM streams; issued before compute)
    u32x2 xpf[2][NGATE];
#pragma unroll
    for (int h2 = 0; h2 < 2; ++h2)
#pragma unroll
      for (int g = 0; g < NGATE; ++g)
        xpf[h2][g] = *reinterpret_cast<const u32x2*>(
            xp + ((size_t)(lt * 4 + wg) * NGT + g * 16 + v + 8 * h2) * 256 + lane * 4);
    float mv[2][4];
#pragma unroll
    for (int h2 = 0; h2 < 2; ++h2) {
      const int col = h2 * 128 + v * 16 + r16;
#pragma unroll
      for (int j = 0; j < 4; ++j)
        mv[h2][j] = mIn[((size_t)s * BATCH + brow + bj0 + j) * HID + col];
    }

    // A fragments from LDS (row = r16, k-bytes g4*16 + ks*64, swizzled)
    i32x4 A[4];
#pragma unroll
    for (int ks = 0; ks < 4; ++ks)
      A[ks] = *reinterpret_cast<const i32x4*>(&hq[p][r16][swz(r16, (g4 + 4 * ks) * 16)]);

#pragma unroll
    for (int h2 = 0; h2 < 2; ++h2) {
      i32x4 acc[NGATE] = {};
#pragma unroll
      for (int ks = 0; ks < 4; ++ks)
#pragma unroll
        for (int g = 0; g < NGATE; ++g)
          acc[g] = __builtin_amdgcn_mfma_i32_16x16x64_i8(A[ks], Wf[h2][g][ks], acc[g], 0, 0, 0);

      const int col = h2 * 128 + v * 16 + r16;
      float hnew[4];
#pragma unroll
      for (int j = 0; j < 4; ++j) {
#define XPV(g) bf2f((uint16_t)((j & 1) ? (xpf[h2][g][j >> 1] >> 16) : (xpf[h2][g][j >> 1] & 0xffff)))
        const float gi = (float)acc[0][j] * sc[h2][0] + XPV(0);
        const float gf = (float)acc[1][j] * sc[h2][1] + XPV(1);
        const float gg = (float)acc[2][j] * sc[h2][2] + XPV(2);
        const float go = (float)acc[3][j] * sc[h2][3] + XPV(3);
        const float gr = (float)acc[4][j] * sc[h2][4] + XPV(4);
#undef XPV
        const float cn = sigm(gf) * c[h2][j] + sigm(gi) * tanh_f(gg) + sigm(gr) * mv[h2][j];
        c[h2][j] = cn;
        hnew[j] = sigm(go) * tanh_f(cn);
      }
      // outputs + quantized h into next LDS buffer
#pragma unroll
      for (int j = 0; j < 4; ++j) {
        seq[((size_t)s * BATCH + brow + bj0 + j) * HID + col] = hnew[j];
        int q = __float2int_rn(hnew[j] * 127.f);
        hq[p ^ 1][bj0 + j][swz(bj0 + j, col)] = (int8_t)q;
      }
      if (s == T_LEN - 1) {
#pragma unroll
        for (int j = 0; j < 4; ++j) {
          hT[(size_t)(brow + bj0 + j) * HID + col] = hnew[j];
          cT[(size_t)(brow + bj0 + j) * HID + col] = c[h2][j];
        }
      }
    }
    __syncthreads();   // publishes hq[p^1] for next step; guards hq[p] reuse
  }

  // persist c for next chunk
#pragma unroll
  for (int h2 = 0; h2 < 2; ++h2)
#pragma unroll
    for (int j = 0; j < 4; ++j)
      cbuf[(size_t)(brow + bj0 + j) * HID + h2 * 128 + v * 16 + r16] = c[h2][j];
}

extern "C" void kernel_launch(void* const* d_in, const int* in_sizes, int n_in,
                              void* d_out, int out_size, void* d_ws, size_t ws_size,
                              hipStream_t stream) {
  (void)in_sizes; (void)n_in; (void)out_size;
  const float* x    = (const float*)d_in[0];
  const float* mIn  = (const float*)d_in[1];
  const float* h0   = (const float*)d_in[2];
  const float* c0   = (const float*)d_in[3];
  const float* Wih  = (const float*)d_in[4];
  const float* Whh  = (const float*)d_in[5];
  const float* bias = (const float*)d_in[6];
  float* out = (float*)d_out;
  float* seq = out;
  float* hT  = out + (size_t)T_LEN * BATCH * HID;
  float* cT  = hT + (size_t)BATCH * HID;

  // ws: xp(bf16) + wihb(bf16) + wq(i8) + wsc(f32) + cbuf(f32)
  const size_t fixed = (size_t)GROWS * KDIM * 2 + (size_t)GROWS * KDIM
                     + (size_t)GROWS * 4 + (size_t)BATCH * HID * 4 + 4096;
  int tchunk = T_LEN;
  while (tchunk > 2 && (size_t)tchunk * BATCH * GROWS * 2 + fixed > ws_size) tchunk >>= 1;

  char* p = (char*)d_ws;
  uint16_t* xp   = (uint16_t*)p;  p += (size_t)tchunk * BATCH * GROWS * 2;
  uint16_t* wihb = (uint16_t*)p;  p += (size_t)GROWS * KDIM * 2;
  int8_t*   wq   = (int8_t*)p;    p += (size_t)GROWS * KDIM;
  float*    wsc  = (float*)p;     p += (size_t)GROWS * 4;
  float*    cbuf = (float*)p;

  setup_kernel<<<dim3((GROWS * KDIM + 255) / 256), dim3(256), 0, stream>>>(
      Wih, c0, wihb, cbuf);
  wquant_kernel<<<dim3((GROWS + 255) / 256), dim3(256), 0, stream>>>(Whh, wq, wsc);
  for (int s0 = 0; s0 < T_LEN; s0 += tchunk) {
    xproj_kernel<<<dim3(tchunk / 2), dim3(256), 0, stream>>>(x, wihb, bias, xp, s0);
    const float* h_src = (s0 == 0) ? h0 : (seq + (size_t)(s0 - 1) * BATCH * HID);
    scan_kernel<<<dim3(NSWG), dim3(512), 0, stream>>>(
        mIn, wq, wsc, xp, h_src, cbuf, seq, hT, cT, s0, s0 + tchunk);
  }
}

// Round 6
// 6256.474 us; speedup vs baseline: 1.0483x; 1.0483x over previous
//
#include <hip/hip_runtime.h>
#include <stdint.h>
#include <stddef.h>

#define T_LEN 1024
#define BATCH 64
#define KDIM  256
#define HID   256
#define NGATE 5
#define GROWS (NGATE * HID)   // 1280
#define NGT   (GROWS / 16)    // 80 gate tiles of 16 rows
#define NSWG  4               // scan WGs: 16 batch rows each, fully independent

typedef __attribute__((ext_vector_type(8))) short s16x8;   // 8 bf16
typedef __attribute__((ext_vector_type(4))) float f32x4;
typedef __attribute__((ext_vector_type(4))) int   i32x4;
typedef __attribute__((ext_vector_type(2))) unsigned int u32x2;

static __device__ __forceinline__ uint16_t f2bf(float f) {
  uint32_t u = __float_as_uint(f);
  return (uint16_t)((u + 0x7fffu + ((u >> 16) & 1u)) >> 16);   // RNE
}
static __device__ __forceinline__ float bf2f(uint16_t b) {
  return __uint_as_float(((uint32_t)b) << 16);
}
static __device__ __forceinline__ s16x8 cvt8(const float* __restrict__ p) {
  float4 a = *reinterpret_cast<const float4*>(p);
  float4 b = *reinterpret_cast<const float4*>(p + 4);
  union { s16x8 v; uint16_t u[8]; } r;
  r.u[0] = f2bf(a.x); r.u[1] = f2bf(a.y); r.u[2] = f2bf(a.z); r.u[3] = f2bf(a.w);
  r.u[4] = f2bf(b.x); r.u[5] = f2bf(b.y); r.u[6] = f2bf(b.z); r.u[7] = f2bf(b.w);
  return r.v;
}
static __device__ __forceinline__ float sigm(float x)   { return 1.f / (1.f + __expf(-x)); }
static __device__ __forceinline__ float tanh_f(float x) { return 1.f - 2.f / (__expf(2.f * x) + 1.f); }
// LDS swizzle: XOR 16B-block index with row (breaks the stride-256B bank collision)
static __device__ __forceinline__ int swz(int row, int col) {
  return ((((col >> 4) ^ (row & 15)) << 4) | (col & 15));
}

// ---------------- setup: W_ih -> bf16, c0 -> cbuf ----------------
__global__ void setup_kernel(const float* __restrict__ Wih, const float* __restrict__ c0,
                             uint16_t* __restrict__ wihb, float* __restrict__ cbuf) {
  int i = blockIdx.x * 256 + threadIdx.x;
  if (i < GROWS * KDIM) wihb[i] = f2bf(Wih[i]);
  if (i < BATCH * HID) cbuf[i] = c0[i];
}

// ---------------- W_hh -> int8 per-row quant ----------------
__global__ void wquant_kernel(const float* __restrict__ Whh,
                              int8_t* __restrict__ wq, float* __restrict__ wsc) {
  int row = blockIdx.x * 256 + threadIdx.x;
  if (row >= GROWS) return;
  const float* wr = Whh + (size_t)row * KDIM;
  float mx = 1e-30f;
  for (int k = 0; k < KDIM; ++k) mx = fmaxf(mx, fabsf(wr[k]));
  wsc[row] = mx / 127.f;
  const float inv = 127.f / mx;
  int8_t* q = wq + (size_t)row * KDIM;
  for (int k = 0; k < KDIM; ++k) q[k] = (int8_t)__float2int_rn(wr[k] * inv);
}

// ---------------- x projection (bf16 MFMA, per-lane C-fragment layout) ----------------
__global__ __launch_bounds__(256, 2)
void xproj_kernel(const float* __restrict__ x, const uint16_t* __restrict__ wihb,
                  const float* __restrict__ bias, uint16_t* __restrict__ xp, int t0) {
  const int w = threadIdx.x >> 6, lane = threadIdx.x & 63;
  const int r16 = lane & 15, ke = (lane >> 4) * 8;
  const int tA = t0 + (int)blockIdx.x * 2;

  s16x8 A[2][8];
#pragma unroll
  for (int tt = 0; tt < 2; ++tt) {
    const float* ap = x + ((size_t)(tA + tt) * BATCH + w * 16 + r16) * KDIM + ke;
#pragma unroll
    for (int ks = 0; ks < 8; ++ks) A[tt][ks] = cvt8(ap + ks * 32);
  }
  for (int gt = 0; gt < NGT; ++gt) {
    const uint16_t* bp = wihb + (size_t)(gt * 16 + r16) * KDIM + ke;
    s16x8 B[8];
#pragma unroll
    for (int ks = 0; ks < 8; ++ks) B[ks] = *reinterpret_cast<const s16x8*>(bp + ks * 32);
    const float bv = bias[gt * 16 + r16];
#pragma unroll
    for (int tt = 0; tt < 2; ++tt) {
      f32x4 acc = {};
#pragma unroll
      for (int ks = 0; ks < 8; ++ks)
        acc = __builtin_amdgcn_mfma_f32_16x16x32_bf16(A[tt][ks], B[ks], acc, 0, 0, 0);
      const int lt = (int)blockIdx.x * 2 + tt;
      uint32_t w0 = (uint32_t)f2bf(acc[0] + bv) | ((uint32_t)f2bf(acc[1] + bv) << 16);
      uint32_t w1 = (uint32_t)f2bf(acc[2] + bv) | ((uint32_t)f2bf(acc[3] + bv) << 16);
      u32x2 pk = {w0, w1};
      u32x2* dst = (u32x2*)((uint32_t*)(xp + ((size_t)(lt * 4 + w) * NGT + gt) * 256) + lane * 2);
      __builtin_nontemporal_store(pk, dst);
    }
  }
}

// ---------------- sequential scan: 4 independent WGs, zero inter-WG traffic ----------------
// WG owns 16 batch rows; 8 waves; wave v owns H-cols [v*16,+16) and [128+v*16,+16).
// All of W_hh resident as i8 VGPR fragments (~160 regs/lane; amdgpu_waves_per_eu(2,2)
// pins the allocator at the 256-reg / 2-waves-per-EU point so it cannot spill-to-128).
// h exchanged via LDS i8 double buffer + one raw s_barrier per step.
__global__ __launch_bounds__(512, 2) __attribute__((amdgpu_waves_per_eu(2, 2)))
void scan_kernel(const float* __restrict__ mIn, const int8_t* __restrict__ wq,
                 const float* __restrict__ wsc, const uint16_t* __restrict__ xp,
                 const float* __restrict__ h_src, float* __restrict__ cbuf,
                 float* __restrict__ seq, float* __restrict__ hT, float* __restrict__ cT,
                 int s0, int s1) {
  __shared__ int8_t hq[2][16][256];   // 8 KB double buffer
  const int wg = blockIdx.x;                // batch tile (16 rows)
  const int v = threadIdx.x >> 6;           // wave 0..7
  const int lane = threadIdx.x & 63;
  const int r16 = lane & 15, g4 = lane >> 4;
  const int bj0 = g4 * 4;                   // batch row (within tile) base, C layout
  const int brow = wg * 16;                 // global batch base

  // Resident W_hh i8 fragments + scales: [half][gate][kstep]
  i32x4 Wf[2][NGATE][4];
  float sc[2][NGATE];
#pragma unroll
  for (int h2 = 0; h2 < 2; ++h2)
#pragma unroll
    for (int g = 0; g < NGATE; ++g) {
      const int grow = g * 256 + (v + 8 * h2) * 16 + r16;
      const int8_t* wp = wq + (size_t)grow * KDIM + g4 * 16;
#pragma unroll
      for (int ks = 0; ks < 4; ++ks)
        Wf[h2][g][ks] = *reinterpret_cast<const i32x4*>(wp + ks * 64);
      sc[h2][g] = wsc[grow] * (1.f / 127.f);
    }

  float c[2][4];
#pragma unroll
  for (int h2 = 0; h2 < 2; ++h2)
#pragma unroll
    for (int j = 0; j < 4; ++j)
      c[h2][j] = cbuf[(size_t)(brow + bj0 + j) * HID + h2 * 128 + v * 16 + r16];

  // cooperative: quantize entry h (h0 or seq[s0-1]) into LDS buf parity s0&1
  {
    const int p0 = s0 & 1;
    for (int e = 0; e < 8; ++e) {
      int t = (int)threadIdx.x * 8 + e;
      int row = t >> 8, col = t & 255;
      float hv = h_src[(size_t)(brow + row) * HID + col];
      int q = __float2int_rn(fminf(fmaxf(hv * 127.f, -127.f), 127.f));
      hq[p0][row][swz(row, col)] = (int8_t)q;
    }
  }
  __syncthreads();

  for (int s = s0; s < s1; ++s) {
    const int lt = s - s0, p = s & 1;
    // issue all global loads for this step up front (xp + m streams)
    u32x2 xpf[2][NGATE];
#pragma unroll
    for (int h2 = 0; h2 < 2; ++h2)
#pragma unroll
      for (int g = 0; g < NGATE; ++g)
        xpf[h2][g] = *reinterpret_cast<const u32x2*>(
            xp + ((size_t)(lt * 4 + wg) * NGT + g * 16 + v + 8 * h2) * 256 + lane * 4);
    float mv[2][4];
#pragma unroll
    for (int h2 = 0; h2 < 2; ++h2) {
      const int col = h2 * 128 + v * 16 + r16;
#pragma unroll
      for (int j = 0; j < 4; ++j)
        mv[h2][j] = mIn[((size_t)s * BATCH + brow + bj0 + j) * HID + col];
    }

    // A fragments from LDS (row = r16, k-bytes (g4+4ks)*16, swizzled)
    i32x4 A[4];
#pragma unroll
    for (int ks = 0; ks < 4; ++ks)
      A[ks] = *reinterpret_cast<const i32x4*>(&hq[p][r16][swz(r16, (g4 + 4 * ks) * 16)]);

#pragma unroll
    for (int h2 = 0; h2 < 2; ++h2) {
      i32x4 acc[NGATE] = {};
      __builtin_amdgcn_s_setprio(1);
#pragma unroll
      for (int ks = 0; ks < 4; ++ks)
#pragma unroll
        for (int g = 0; g < NGATE; ++g)
          acc[g] = __builtin_amdgcn_mfma_i32_16x16x64_i8(A[ks], Wf[h2][g][ks], acc[g], 0, 0, 0);
      __builtin_amdgcn_s_setprio(0);

      const int col = h2 * 128 + v * 16 + r16;
      float hnew[4];
#pragma unroll
      for (int j = 0; j < 4; ++j) {
#define XPV(g) bf2f((uint16_t)((j & 1) ? (xpf[h2][g][j >> 1] >> 16) : (xpf[h2][g][j >> 1] & 0xffff)))
        const float gi = (float)acc[0][j] * sc[h2][0] + XPV(0);
        const float gf = (float)acc[1][j] * sc[h2][1] + XPV(1);
        const float gg = (float)acc[2][j] * sc[h2][2] + XPV(2);
        const float go = (float)acc[3][j] * sc[h2][3] + XPV(3);
        const float gr = (float)acc[4][j] * sc[h2][4] + XPV(4);
#undef XPV
        const float cn = sigm(gf) * c[h2][j] + sigm(gi) * tanh_f(gg) + sigm(gr) * mv[h2][j];
        c[h2][j] = cn;
        hnew[j] = sigm(go) * tanh_f(cn);
      }
      // outputs + quantized h into next LDS buffer (global stores are fire-and-forget)
#pragma unroll
      for (int j = 0; j < 4; ++j) {
        __builtin_nontemporal_store(hnew[j], seq + ((size_t)s * BATCH + brow + bj0 + j) * HID + col);
        int q = __float2int_rn(hnew[j] * 127.f);
        hq[p ^ 1][bj0 + j][swz(bj0 + j, col)] = (int8_t)q;
      }
      if (s == T_LEN - 1) {
#pragma unroll
        for (int j = 0; j < 4; ++j) {
          hT[(size_t)(brow + bj0 + j) * HID + col] = hnew[j];
          cT[(size_t)(brow + bj0 + j) * HID + col] = c[h2][j];
        }
      }
    }
    // raw barrier: only LDS ordering needed (global stores keep flying)
    __builtin_amdgcn_sched_barrier(0);
    asm volatile("s_waitcnt lgkmcnt(0)" ::: "memory");
    __builtin_amdgcn_s_barrier();
    __builtin_amdgcn_sched_barrier(0);
  }

  // persist c for next chunk
#pragma unroll
  for (int h2 = 0; h2 < 2; ++h2)
#pragma unroll
    for (int j = 0; j < 4; ++j)
      cbuf[(size_t)(brow + bj0 + j) * HID + h2 * 128 + v * 16 + r16] = c[h2][j];
}

extern "C" void kernel_launch(void* const* d_in, const int* in_sizes, int n_in,
                              void* d_out, int out_size, void* d_ws, size_t ws_size,
                              hipStream_t stream) {
  (void)in_sizes; (void)n_in; (void)out_size;
  const float* x    = (const float*)d_in[0];
  const float* mIn  = (const float*)d_in[1];
  const float* h0   = (const float*)d_in[2];
  const float* c0   = (const float*)d_in[3];
  const float* Wih  = (const float*)d_in[4];
  const float* Whh  = (const float*)d_in[5];
  const float* bias = (const float*)d_in[6];
  float* out = (float*)d_out;
  float* seq = out;
  float* hT  = out + (size_t)T_LEN * BATCH * HID;
  float* cT  = hT + (size_t)BATCH * HID;

  // ws: xp(bf16) + wihb(bf16) + wq(i8) + wsc(f32) + cbuf(f32)
  const size_t fixed = (size_t)GROWS * KDIM * 2 + (size_t)GROWS * KDIM
                     + (size_t)GROWS * 4 + (size_t)BATCH * HID * 4 + 4096;
  int tchunk = T_LEN;
  while (tchunk > 2 && (size_t)tchunk * BATCH * GROWS * 2 + fixed > ws_size) tchunk >>= 1;

  char* p = (char*)d_ws;
  uint16_t* xp   = (uint16_t*)p;  p += (size_t)tchunk * BATCH * GROWS * 2;
  uint16_t* wihb = (uint16_t*)p;  p += (size_t)GROWS * KDIM * 2;
  int8_t*   wq   = (int8_t*)p;    p += (size_t)GROWS * KDIM;
  float*    wsc  = (float*)p;     p += (size_t)GROWS * 4;
  float*    cbuf = (float*)p;

  setup_kernel<<<dim3((GROWS * KDIM + 255) / 256), dim3(256), 0, stream>>>(
      Wih, c0, wihb, cbuf);
  wquant_kernel<<<dim3((GROWS + 255) / 256), dim3(256), 0, stream>>>(Whh, wq, wsc);
  for (int s0 = 0; s0 < T_LEN; s0 += tchunk) {
    xproj_kernel<<<dim3(tchunk / 2), dim3(256), 0, stream>>>(x, wihb, bias, xp, s0);
    const float* h_src = (s0 == 0) ? h0 : (seq + (size_t)(s0 - 1) * BATCH * HID);
    scan_kernel<<<dim3(NSWG), dim3(512), 0, stream>>>(
        mIn, wq, wsc, xp, h_src, cbuf, seq, hT, cT, s0, s0 + tchunk);
  }
}

// Round 7
// 4851.884 us; speedup vs baseline: 1.3517x; 1.2895x over previous
//
#include <hip/hip_runtime.h>
#include <stdint.h>
#include <stddef.h>

#define T_LEN 1024
#define BATCH 64
#define KDIM  256
#define HID   256
#define NGATE 5
#define GROWS (NGATE * HID)   // 1280
#define NGT   (GROWS / 16)    // 80 gate tiles of 16 rows
#define NSWG  4               // scan WGs: 16 batch rows each, fully independent

typedef __attribute__((ext_vector_type(8))) short s16x8;   // 8 bf16
typedef __attribute__((ext_vector_type(4))) float f32x4;
typedef __attribute__((ext_vector_type(4))) int   i32x4;
typedef __attribute__((ext_vector_type(2))) unsigned int u32x2;

static __device__ __forceinline__ uint16_t f2bf(float f) {
  uint32_t u = __float_as_uint(f);
  return (uint16_t)((u + 0x7fffu + ((u >> 16) & 1u)) >> 16);   // RNE
}
static __device__ __forceinline__ float bf2f(uint16_t b) {
  return __uint_as_float(((uint32_t)b) << 16);
}
static __device__ __forceinline__ s16x8 cvt8(const float* __restrict__ p) {
  float4 a = *reinterpret_cast<const float4*>(p);
  float4 b = *reinterpret_cast<const float4*>(p + 4);
  union { s16x8 v; uint16_t u[8]; } r;
  r.u[0] = f2bf(a.x); r.u[1] = f2bf(a.y); r.u[2] = f2bf(a.z); r.u[3] = f2bf(a.w);
  r.u[4] = f2bf(b.x); r.u[5] = f2bf(b.y); r.u[6] = f2bf(b.z); r.u[7] = f2bf(b.w);
  return r.v;
}
static __device__ __forceinline__ float sigm(float x)   { return 1.f / (1.f + __expf(-x)); }
static __device__ __forceinline__ float tanh_f(float x) { return 1.f - 2.f / (__expf(2.f * x) + 1.f); }
// LDS swizzle for hq: XOR 16B-block index with row (breaks stride-256B bank collision)
static __device__ __forceinline__ int swz(int row, int col) {
  return ((((col >> 4) ^ (row & 15)) << 4) | (col & 15));
}

// ---------------- setup: W_ih -> bf16, c0 -> cbuf ----------------
__global__ void setup_kernel(const float* __restrict__ Wih, const float* __restrict__ c0,
                             uint16_t* __restrict__ wihb, float* __restrict__ cbuf) {
  int i = blockIdx.x * 256 + threadIdx.x;
  if (i < GROWS * KDIM) wihb[i] = f2bf(Wih[i]);
  if (i < BATCH * HID) cbuf[i] = c0[i];
}

// ---------------- W_hh -> int8 per-row quant ----------------
__global__ void wquant_kernel(const float* __restrict__ Whh,
                              int8_t* __restrict__ wq, float* __restrict__ wsc) {
  int row = blockIdx.x * 256 + threadIdx.x;
  if (row >= GROWS) return;
  const float* wr = Whh + (size_t)row * KDIM;
  float mx = 1e-30f;
  for (int k = 0; k < KDIM; ++k) mx = fmaxf(mx, fabsf(wr[k]));
  wsc[row] = mx / 127.f;
  const float inv = 127.f / mx;
  int8_t* q = wq + (size_t)row * KDIM;
  for (int k = 0; k < KDIM; ++k) q[k] = (int8_t)__float2int_rn(wr[k] * inv);
}

// ---------------- x projection (bf16 MFMA, per-lane C-fragment layout) ----------------
__global__ __launch_bounds__(256, 2)
void xproj_kernel(const float* __restrict__ x, const uint16_t* __restrict__ wihb,
                  const float* __restrict__ bias, uint16_t* __restrict__ xp, int t0) {
  const int w = threadIdx.x >> 6, lane = threadIdx.x & 63;
  const int r16 = lane & 15, ke = (lane >> 4) * 8;
  const int tA = t0 + (int)blockIdx.x * 2;

  s16x8 A[2][8];
#pragma unroll
  for (int tt = 0; tt < 2; ++tt) {
    const float* ap = x + ((size_t)(tA + tt) * BATCH + w * 16 + r16) * KDIM + ke;
#pragma unroll
    for (int ks = 0; ks < 8; ++ks) A[tt][ks] = cvt8(ap + ks * 32);
  }
  for (int gt = 0; gt < NGT; ++gt) {
    const uint16_t* bp = wihb + (size_t)(gt * 16 + r16) * KDIM + ke;
    s16x8 B[8];
#pragma unroll
    for (int ks = 0; ks < 8; ++ks) B[ks] = *reinterpret_cast<const s16x8*>(bp + ks * 32);
    const float bv = bias[gt * 16 + r16];
#pragma unroll
    for (int tt = 0; tt < 2; ++tt) {
      f32x4 acc = {};
#pragma unroll
      for (int ks = 0; ks < 8; ++ks)
        acc = __builtin_amdgcn_mfma_f32_16x16x32_bf16(A[tt][ks], B[ks], acc, 0, 0, 0);
      const int lt = (int)blockIdx.x * 2 + tt;
      uint32_t w0 = (uint32_t)f2bf(acc[0] + bv) | ((uint32_t)f2bf(acc[1] + bv) << 16);
      uint32_t w1 = (uint32_t)f2bf(acc[2] + bv) | ((uint32_t)f2bf(acc[3] + bv) << 16);
      u32x2 pk = {w0, w1};
      u32x2* dst = (u32x2*)((uint32_t*)(xp + ((size_t)(lt * 4 + w) * NGT + gt) * 256) + lane * 2);
      __builtin_nontemporal_store(pk, dst);
    }
  }
}

// ---------------- sequential scan: 4 independent WGs, zero inter-WG traffic ----------------
// WG owns 16 batch rows; 8 waves; wave v owns H-cols [v*16,+16) and [128+v*16,+16).
// Weights i8, split: gates {i,f,g} resident in VGPRs (96 regs/lane); gates {o,r} in
// LDS (128 KB, per-lane fragment order, conflict-free ds_read_b128). h exchanged via
// LDS i8 double buffer + one raw s_barrier per step.
__global__ __launch_bounds__(512, 2)
void scan_kernel(const float* __restrict__ mIn, const int8_t* __restrict__ wq,
                 const float* __restrict__ wsc, const uint16_t* __restrict__ xp,
                 const float* __restrict__ h_src, float* __restrict__ cbuf,
                 float* __restrict__ seq, float* __restrict__ hT, float* __restrict__ cT,
                 int s0, int s1) {
  struct SW {
    int8_t w[8][2][2][4][1024];   // [wave][half][ldsgate][ks][lane*16]  128 KB
    int8_t hq[2][16][256];        // h double buffer, swizzled            8 KB
  };
  __shared__ SW sl;
  const int wg = blockIdx.x;                // batch tile (16 rows)
  const int v = threadIdx.x >> 6;           // wave 0..7
  const int lane = threadIdx.x & 63;
  const int r16 = lane & 15, g4 = lane >> 4;
  const int bj0 = g4 * 4;                   // batch row (within tile) base, C layout
  const int brow = wg * 16;                 // global batch base

  // VGPR-resident gates 0..2 + all scales
  i32x4 Wf[2][3][4];
  float sc[2][NGATE];
#pragma unroll
  for (int h2 = 0; h2 < 2; ++h2)
#pragma unroll
    for (int g = 0; g < NGATE; ++g) {
      const int grow = g * 256 + (v + 8 * h2) * 16 + r16;
      if (g < 3) {
        const int8_t* wp = wq + (size_t)grow * KDIM + g4 * 16;
#pragma unroll
        for (int ks = 0; ks < 4; ++ks)
          Wf[h2][g][ks] = *reinterpret_cast<const i32x4*>(wp + ks * 64);
      }
      sc[h2][g] = wsc[grow] * (1.f / 127.f);
    }
  // LDS-resident gates 3,4: write own fragments in per-lane order
#pragma unroll
  for (int h2 = 0; h2 < 2; ++h2)
#pragma unroll
    for (int gl = 0; gl < 2; ++gl) {
      const int grow = (3 + gl) * 256 + (v + 8 * h2) * 16 + r16;
      const int8_t* wp = wq + (size_t)grow * KDIM + g4 * 16;
#pragma unroll
      for (int ks = 0; ks < 4; ++ks)
        *reinterpret_cast<i32x4*>(&sl.w[v][h2][gl][ks][lane * 16]) =
            *reinterpret_cast<const i32x4*>(wp + ks * 64);
    }

  float c[2][4];
#pragma unroll
  for (int h2 = 0; h2 < 2; ++h2)
#pragma unroll
    for (int j = 0; j < 4; ++j)
      c[h2][j] = cbuf[(size_t)(brow + bj0 + j) * HID + h2 * 128 + v * 16 + r16];

  // entry h (h0 or seq[s0-1]) -> quantized into LDS buf parity s0&1
  {
    const int p0 = s0 & 1;
    for (int e = 0; e < 8; ++e) {
      int t = (int)threadIdx.x * 8 + e;
      int row = t >> 8, col = t & 255;
      float hv = h_src[(size_t)(brow + row) * HID + col];
      int q = __float2int_rn(fminf(fmaxf(hv * 127.f, -127.f), 127.f));
      sl.hq[p0][row][swz(row, col)] = (int8_t)q;
    }
  }
  __syncthreads();

  // stepping pointers (constant strides; per-load offsets are compile-time)
  const uint16_t* xpb = xp + ((size_t)wg * NGT + v) * 256 + lane * 4;
  const float*    mb  = mIn + ((size_t)s0 * BATCH + brow + bj0) * HID + v * 16 + r16;
  float*          sqb = seq + ((size_t)s0 * BATCH + brow + bj0) * HID + v * 16 + r16;

  for (int s = s0; s < s1; ++s) {
    const int p = s & 1;
    // global prefetch: xp fragments + m values
    u32x2 xpf[2][NGATE];
#pragma unroll
    for (int h2 = 0; h2 < 2; ++h2)
#pragma unroll
      for (int g = 0; g < NGATE; ++g)
        xpf[h2][g] = *reinterpret_cast<const u32x2*>(xpb + (g * 16 + 8 * h2) * 256);
    float mv[2][4];
#pragma unroll
    for (int h2 = 0; h2 < 2; ++h2)
#pragma unroll
      for (int j = 0; j < 4; ++j)
        mv[h2][j] = mb[j * HID + h2 * 128];

    // A fragments from LDS (row r16, k-bytes (g4+4ks)*16, swizzled)
    i32x4 A[4];
#pragma unroll
    for (int ks = 0; ks < 4; ++ks)
      A[ks] = *reinterpret_cast<const i32x4*>(&sl.hq[p][r16][swz(r16, (g4 + 4 * ks) * 16)]);

#pragma unroll
    for (int h2 = 0; h2 < 2; ++h2) {
      // LDS B fragments for gates o,r of this half
      i32x4 Bl[2][4];
#pragma unroll
      for (int gl = 0; gl < 2; ++gl)
#pragma unroll
        for (int ks = 0; ks < 4; ++ks)
          Bl[gl][ks] = *reinterpret_cast<const i32x4*>(&sl.w[v][h2][gl][ks][lane * 16]);

      i32x4 acc[NGATE] = {};
      __builtin_amdgcn_s_setprio(1);
#pragma unroll
      for (int ks = 0; ks < 4; ++ks)
#pragma unroll
        for (int g = 0; g < 3; ++g)
          acc[g] = __builtin_amdgcn_mfma_i32_16x16x64_i8(A[ks], Wf[h2][g][ks], acc[g], 0, 0, 0);
#pragma unroll
      for (int ks = 0; ks < 4; ++ks)
#pragma unroll
        for (int gl = 0; gl < 2; ++gl)
          acc[3 + gl] = __builtin_amdgcn_mfma_i32_16x16x64_i8(A[ks], Bl[gl][ks], acc[3 + gl], 0, 0, 0);
      __builtin_amdgcn_s_setprio(0);

      const int col = h2 * 128 + v * 16 + r16;
      float hnew[4];
#pragma unroll
      for (int j = 0; j < 4; ++j) {
#define XPV(g) bf2f((uint16_t)((j & 1) ? (xpf[h2][g][j >> 1] >> 16) : (xpf[h2][g][j >> 1] & 0xffff)))
        const float gi = (float)acc[0][j] * sc[h2][0] + XPV(0);
        const float gf = (float)acc[1][j] * sc[h2][1] + XPV(1);
        const float gg = (float)acc[2][j] * sc[h2][2] + XPV(2);
        const float go = (float)acc[3][j] * sc[h2][3] + XPV(3);
        const float gr = (float)acc[4][j] * sc[h2][4] + XPV(4);
#undef XPV
        const float cn = sigm(gf) * c[h2][j] + sigm(gi) * tanh_f(gg) + sigm(gr) * mv[h2][j];
        c[h2][j] = cn;
        hnew[j] = sigm(go) * tanh_f(cn);
      }
#pragma unroll
      for (int j = 0; j < 4; ++j) {
        __builtin_nontemporal_store(hnew[j], sqb + j * HID + h2 * 128);
        int q = __float2int_rn(hnew[j] * 127.f);
        sl.hq[p ^ 1][bj0 + j][swz(bj0 + j, col)] = (int8_t)q;
      }
      if (s == T_LEN - 1) {
#pragma unroll
        for (int j = 0; j < 4; ++j) {
          hT[(size_t)(brow + bj0 + j) * HID + col] = hnew[j];
          cT[(size_t)(brow + bj0 + j) * HID + col] = c[h2][j];
        }
      }
    }
    // raw barrier: only LDS ordering needed (global stores keep flying)
    __builtin_amdgcn_sched_barrier(0);
    asm volatile("s_waitcnt lgkmcnt(0)" ::: "memory");
    __builtin_amdgcn_s_barrier();
    __builtin_amdgcn_sched_barrier(0);
    xpb += 4 * NGT * 256;
    mb  += BATCH * HID;
    sqb += BATCH * HID;
  }

  // persist c for next chunk
#pragma unroll
  for (int h2 = 0; h2 < 2; ++h2)
#pragma unroll
    for (int j = 0; j < 4; ++j)
      cbuf[(size_t)(brow + bj0 + j) * HID + h2 * 128 + v * 16 + r16] = c[h2][j];
}

extern "C" void kernel_launch(void* const* d_in, const int* in_sizes, int n_in,
                              void* d_out, int out_size, void* d_ws, size_t ws_size,
                              hipStream_t stream) {
  (void)in_sizes; (void)n_in; (void)out_size;
  const float* x    = (const float*)d_in[0];
  const float* mIn  = (const float*)d_in[1];
  const float* h0   = (const float*)d_in[2];
  const float* c0   = (const float*)d_in[3];
  const float* Wih  = (const float*)d_in[4];
  const float* Whh  = (const float*)d_in[5];
  const float* bias = (const float*)d_in[6];
  float* out = (float*)d_out;
  float* seq = out;
  float* hT  = out + (size_t)T_LEN * BATCH * HID;
  float* cT  = hT + (size_t)BATCH * HID;

  // ws: xp(bf16) + wihb(bf16) + wq(i8) + wsc(f32) + cbuf(f32)
  const size_t fixed = (size_t)GROWS * KDIM * 2 + (size_t)GROWS * KDIM
                     + (size_t)GROWS * 4 + (size_t)BATCH * HID * 4 + 4096;
  int tchunk = T_LEN;
  while (tchunk > 2 && (size_t)tchunk * BATCH * GROWS * 2 + fixed > ws_size) tchunk >>= 1;

  char* p = (char*)d_ws;
  uint16_t* xp   = (uint16_t*)p;  p += (size_t)tchunk * BATCH * GROWS * 2;
  uint16_t* wihb = (uint16_t*)p;  p += (size_t)GROWS * KDIM * 2;
  int8_t*   wq   = (int8_t*)p;    p += (size_t)GROWS * KDIM;
  float*    wsc  = (float*)p;     p += (size_t)GROWS * 4;
  float*    cbuf = (float*)p;

  setup_kernel<<<dim3((GROWS * KDIM + 255) / 256), dim3(256), 0, stream>>>(
      Wih, c0, wihb, cbuf);
  wquant_kernel<<<dim3((GROWS + 255) / 256), dim3(256), 0, stream>>>(Whh, wq, wsc);
  for (int s0 = 0; s0 < T_LEN; s0 += tchunk) {
    xproj_kernel<<<dim3(tchunk / 2), dim3(256), 0, stream>>>(x, wihb, bias, xp, s0);
    const float* h_src = (s0 == 0) ? h0 : (seq + (size_t)(s0 - 1) * BATCH * HID);
    scan_kernel<<<dim3(NSWG), dim3(512), 0, stream>>>(
        mIn, wq, wsc, xp, h_src, cbuf, seq, hT, cT, s0, s0 + tchunk);
  }
}

// Round 8
// 4004.166 us; speedup vs baseline: 1.6379x; 1.2117x over previous
//
#include <hip/hip_runtime.h>
#include <stdint.h>
#include <stddef.h>

#define T_LEN 1024
#define BATCH 64
#define KDIM  256
#define HID   256
#define NGATE 5
#define GROWS (NGATE * HID)   // 1280
#define NGT   (GROWS / 16)    // 80 gate tiles of 16 rows
#define NSWG  4               // scan WGs: 16 batch rows each, fully independent

typedef __attribute__((ext_vector_type(8))) short s16x8;   // 8 bf16
typedef __attribute__((ext_vector_type(4))) float f32x4;
typedef __attribute__((ext_vector_type(4))) int   i32x4;
typedef __attribute__((ext_vector_type(2))) unsigned int u32x2;

static __device__ __forceinline__ uint16_t f2bf(float f) {
  uint32_t u = __float_as_uint(f);
  return (uint16_t)((u + 0x7fffu + ((u >> 16) & 1u)) >> 16);   // RNE
}
static __device__ __forceinline__ float bf2f(uint16_t b) {
  return __uint_as_float(((uint32_t)b) << 16);
}
static __device__ __forceinline__ s16x8 cvt8(const float* __restrict__ p) {
  float4 a = *reinterpret_cast<const float4*>(p);
  float4 b = *reinterpret_cast<const float4*>(p + 4);
  union { s16x8 v; uint16_t u[8]; } r;
  r.u[0] = f2bf(a.x); r.u[1] = f2bf(a.y); r.u[2] = f2bf(a.z); r.u[3] = f2bf(a.w);
  r.u[4] = f2bf(b.x); r.u[5] = f2bf(b.y); r.u[6] = f2bf(b.z); r.u[7] = f2bf(b.w);
  return r.v;
}
static __device__ __forceinline__ float sigm(float x)   { return 1.f / (1.f + __expf(-x)); }
static __device__ __forceinline__ float tanh_f(float x) { return 1.f - 2.f / (__expf(2.f * x) + 1.f); }
// LDS swizzle for hq: XOR 16B-block index with row (breaks stride-256B bank collision)
static __device__ __forceinline__ int swz(int row, int col) {
  return ((((col >> 4) ^ (row & 15)) << 4) | (col & 15));
}

// ---------------- setup: W_ih -> bf16, c0 -> cbuf ----------------
__global__ void setup_kernel(const float* __restrict__ Wih, const float* __restrict__ c0,
                             uint16_t* __restrict__ wihb, float* __restrict__ cbuf) {
  int i = blockIdx.x * 256 + threadIdx.x;
  if (i < GROWS * KDIM) wihb[i] = f2bf(Wih[i]);
  if (i < BATCH * HID) cbuf[i] = c0[i];
}

// ---------------- W_hh -> int8 per-row quant ----------------
__global__ void wquant_kernel(const float* __restrict__ Whh,
                              int8_t* __restrict__ wq, float* __restrict__ wsc) {
  int row = blockIdx.x * 256 + threadIdx.x;
  if (row >= GROWS) return;
  const float* wr = Whh + (size_t)row * KDIM;
  float mx = 1e-30f;
  for (int k = 0; k < KDIM; ++k) mx = fmaxf(mx, fabsf(wr[k]));
  wsc[row] = mx / 127.f;
  const float inv = 127.f / mx;
  int8_t* q = wq + (size_t)row * KDIM;
  for (int k = 0; k < KDIM; ++k) q[k] = (int8_t)__float2int_rn(wr[k] * inv);
}

// ---------------- x projection (bf16 MFMA, per-lane C-fragment layout) ----------------
__global__ __launch_bounds__(256, 2)
void xproj_kernel(const float* __restrict__ x, const uint16_t* __restrict__ wihb,
                  const float* __restrict__ bias, uint16_t* __restrict__ xp, int t0) {
  const int w = threadIdx.x >> 6, lane = threadIdx.x & 63;
  const int r16 = lane & 15, ke = (lane >> 4) * 8;
  const int tA = t0 + (int)blockIdx.x * 2;

  s16x8 A[2][8];
#pragma unroll
  for (int tt = 0; tt < 2; ++tt) {
    const float* ap = x + ((size_t)(tA + tt) * BATCH + w * 16 + r16) * KDIM + ke;
#pragma unroll
    for (int ks = 0; ks < 8; ++ks) A[tt][ks] = cvt8(ap + ks * 32);
  }
  for (int gt = 0; gt < NGT; ++gt) {
    const uint16_t* bp = wihb + (size_t)(gt * 16 + r16) * KDIM + ke;
    s16x8 B[8];
#pragma unroll
    for (int ks = 0; ks < 8; ++ks) B[ks] = *reinterpret_cast<const s16x8*>(bp + ks * 32);
    const float bv = bias[gt * 16 + r16];
#pragma unroll
    for (int tt = 0; tt < 2; ++tt) {
      f32x4 acc = {};
#pragma unroll
      for (int ks = 0; ks < 8; ++ks)
        acc = __builtin_amdgcn_mfma_f32_16x16x32_bf16(A[tt][ks], B[ks], acc, 0, 0, 0);
      const int lt = (int)blockIdx.x * 2 + tt;
      uint32_t w0 = (uint32_t)f2bf(acc[0] + bv) | ((uint32_t)f2bf(acc[1] + bv) << 16);
      uint32_t w1 = (uint32_t)f2bf(acc[2] + bv) | ((uint32_t)f2bf(acc[3] + bv) << 16);
      u32x2 pk = {w0, w1};
      u32x2* dst = (u32x2*)((uint32_t*)(xp + ((size_t)(lt * 4 + w) * NGT + gt) * 256) + lane * 2);
      __builtin_nontemporal_store(pk, dst);
    }
  }
}

// ---------------- sequential scan: 4 independent WGs, 16 waves each ----------------
// WG owns 16 batch rows; wave v owns H-cols [v*16, v*16+16), all 5 gates (j = 4 rows/lane).
// Weights i8: gates {i,f,g} VGPR-resident (48 regs/lane); {o,r} in LDS fragments.
// h via LDS i8 double buffer + one raw s_barrier/step. xp/m prefetched 1 step ahead.
// 1024 threads => 4 waves/SIMD => 128-VGPR budget BY DESIGN (no spill pressure).
__global__ __launch_bounds__(1024, 4)
void scan_kernel(const float* __restrict__ mIn, const int8_t* __restrict__ wq,
                 const float* __restrict__ wsc, const uint16_t* __restrict__ xp,
                 const float* __restrict__ h_src, float* __restrict__ cbuf,
                 float* __restrict__ seq, float* __restrict__ hT, float* __restrict__ cT,
                 int s0, int s1) {
  struct SW {
    int8_t w[16][2][4][1024];   // [wave][ldsgate][ks][lane*16]  128 KB
    int8_t hq[2][16][256];      // h double buffer, swizzled       8 KB
  };
  __shared__ SW sl;
  const int wg = blockIdx.x;                // batch tile (16 rows)
  const int v = threadIdx.x >> 6;           // wave 0..15 = H col-block
  const int lane = threadIdx.x & 63;
  const int r16 = lane & 15, g4 = lane >> 4;
  const int bj0 = g4 * 4;                   // batch row (within tile) base, C layout
  const int brow = wg * 16;                 // global batch base
  const int col = v * 16 + r16;             // owned H column

  // VGPR-resident gates 0..2 + all scales
  i32x4 Wf[3][4];
  float sc[NGATE];
#pragma unroll
  for (int g = 0; g < NGATE; ++g) {
    const int grow = g * 256 + col;
    if (g < 3) {
      const int8_t* wp = wq + (size_t)grow * KDIM + g4 * 16;
#pragma unroll
      for (int ks = 0; ks < 4; ++ks)
        Wf[g][ks] = *reinterpret_cast<const i32x4*>(wp + ks * 64);
    }
    sc[g] = wsc[grow] * (1.f / 127.f);
  }
  // LDS-resident gates 3,4: each wave writes its own fragments in per-lane order
#pragma unroll
  for (int gl = 0; gl < 2; ++gl) {
    const int grow = (3 + gl) * 256 + col;
    const int8_t* wp = wq + (size_t)grow * KDIM + g4 * 16;
#pragma unroll
    for (int ks = 0; ks < 4; ++ks)
      *reinterpret_cast<i32x4*>(&sl.w[v][gl][ks][lane * 16]) =
          *reinterpret_cast<const i32x4*>(wp + ks * 64);
  }

  float c[4];
#pragma unroll
  for (int j = 0; j < 4; ++j)
    c[j] = cbuf[(size_t)(brow + bj0 + j) * HID + col];

  // entry h (h0 or seq[s0-1]) -> quantized into LDS buf parity s0&1
  {
    const int p0 = s0 & 1;
#pragma unroll
    for (int e = 0; e < 4; ++e) {
      int t = (int)threadIdx.x * 4 + e;
      int row = t >> 8, cc = t & 255;
      float hv = h_src[(size_t)(brow + row) * HID + cc];
      int q = __float2int_rn(fminf(fmaxf(hv * 127.f, -127.f), 127.f));
      sl.hq[p0][row][swz(row, cc)] = (int8_t)q;
    }
  }
  __syncthreads();

  // stepping pointers
  const uint16_t* xpb = xp + ((size_t)wg * NGT + v) * 256 + lane * 4;
  const float*    mb  = mIn + ((size_t)s0 * BATCH + brow + bj0) * HID + col;
  float*          sqb = seq + ((size_t)s0 * BATCH + brow + bj0) * HID + col;

  // prologue prefetch for step s0
  u32x2 xpf[NGATE];
  float mv[4];
#pragma unroll
  for (int g = 0; g < NGATE; ++g)
    xpf[g] = *reinterpret_cast<const u32x2*>(xpb + g * 16 * 256);
#pragma unroll
  for (int j = 0; j < 4; ++j) mv[j] = mb[j * HID];

  for (int s = s0; s < s1; ++s) {
    const int p = s & 1;

    // MFMA phase: A from hq, weights from VGPR (gates 0-2) and LDS (gates 3-4)
    i32x4 acc[NGATE] = {};
    __builtin_amdgcn_s_setprio(1);
#pragma unroll
    for (int ks = 0; ks < 4; ++ks) {
      i32x4 A = *reinterpret_cast<const i32x4*>(&sl.hq[p][r16][swz(r16, (g4 + 4 * ks) * 16)]);
      acc[0] = __builtin_amdgcn_mfma_i32_16x16x64_i8(A, Wf[0][ks], acc[0], 0, 0, 0);
      acc[1] = __builtin_amdgcn_mfma_i32_16x16x64_i8(A, Wf[1][ks], acc[1], 0, 0, 0);
      acc[2] = __builtin_amdgcn_mfma_i32_16x16x64_i8(A, Wf[2][ks], acc[2], 0, 0, 0);
      i32x4 b0 = *reinterpret_cast<const i32x4*>(&sl.w[v][0][ks][lane * 16]);
      acc[3] = __builtin_amdgcn_mfma_i32_16x16x64_i8(A, b0, acc[3], 0, 0, 0);
      i32x4 b1 = *reinterpret_cast<const i32x4*>(&sl.w[v][1][ks][lane * 16]);
      acc[4] = __builtin_amdgcn_mfma_i32_16x16x64_i8(A, b1, acc[4], 0, 0, 0);
    }
    __builtin_amdgcn_s_setprio(0);

    // gate math (consumes xpf/mv prefetched one step ago)
    float hnew[4];
#pragma unroll
    for (int j = 0; j < 4; ++j) {
#define XPV(g) bf2f((uint16_t)((j & 1) ? (xpf[g][j >> 1] >> 16) : (xpf[g][j >> 1] & 0xffff)))
      const float gi = (float)acc[0][j] * sc[0] + XPV(0);
      const float gf = (float)acc[1][j] * sc[1] + XPV(1);
      const float gg = (float)acc[2][j] * sc[2] + XPV(2);
      const float go = (float)acc[3][j] * sc[3] + XPV(3);
      const float gr = (float)acc[4][j] * sc[4] + XPV(4);
#undef XPV
      const float cn = sigm(gf) * c[j] + sigm(gi) * tanh_f(gg) + sigm(gr) * mv[j];
      c[j] = cn;
      hnew[j] = sigm(go) * tanh_f(cn);
    }

    // prefetch next step into the (now free) xpf/mv regs — overlaps barrier + next MFMA
    const uint16_t* xpb_n = xpb + 4 * NGT * 256;                 // beyond-chunk read stays in ws
    const float*    mb_n  = (s + 1 < s1) ? mb + BATCH * HID : mb;
#pragma unroll
    for (int g = 0; g < NGATE; ++g)
      xpf[g] = *reinterpret_cast<const u32x2*>(xpb_n + g * 16 * 256);
#pragma unroll
    for (int j = 0; j < 4; ++j) mv[j] = mb_n[j * HID];
    xpb = xpb_n; mb = mb_n;

    // outputs + quantized h into next LDS buffer
#pragma unroll
    for (int j = 0; j < 4; ++j) {
      __builtin_nontemporal_store(hnew[j], sqb + j * HID);
      int q = __float2int_rn(hnew[j] * 127.f);
      sl.hq[p ^ 1][bj0 + j][swz(bj0 + j, col)] = (int8_t)q;
    }
    if (s == T_LEN - 1) {
#pragma unroll
      for (int j = 0; j < 4; ++j) {
        hT[(size_t)(brow + bj0 + j) * HID + col] = hnew[j];
        cT[(size_t)(brow + bj0 + j) * HID + col] = c[j];
      }
    }
    sqb += BATCH * HID;

    // raw barrier: only LDS ordering needed (global loads/stores keep flying)
    __builtin_amdgcn_sched_barrier(0);
    asm volatile("s_waitcnt lgkmcnt(0)" ::: "memory");
    __builtin_amdgcn_s_barrier();
    __builtin_amdgcn_sched_barrier(0);
  }

  // persist c for next chunk
#pragma unroll
  for (int j = 0; j < 4; ++j)
    cbuf[(size_t)(brow + bj0 + j) * HID + col] = c[j];
}

extern "C" void kernel_launch(void* const* d_in, const int* in_sizes, int n_in,
                              void* d_out, int out_size, void* d_ws, size_t ws_size,
                              hipStream_t stream) {
  (void)in_sizes; (void)n_in; (void)out_size;
  const float* x    = (const float*)d_in[0];
  const float* mIn  = (const float*)d_in[1];
  const float* h0   = (const float*)d_in[2];
  const float* c0   = (const float*)d_in[3];
  const float* Wih  = (const float*)d_in[4];
  const float* Whh  = (const float*)d_in[5];
  const float* bias = (const float*)d_in[6];
  float* out = (float*)d_out;
  float* seq = out;
  float* hT  = out + (size_t)T_LEN * BATCH * HID;
  float* cT  = hT + (size_t)BATCH * HID;

  // ws: xp(bf16) + wihb(bf16) + wq(i8) + wsc(f32) + cbuf(f32)
  const size_t fixed = (size_t)GROWS * KDIM * 2 + (size_t)GROWS * KDIM
                     + (size_t)GROWS * 4 + (size_t)BATCH * HID * 4 + 4096;
  int tchunk = T_LEN;
  while (tchunk > 2 && (size_t)tchunk * BATCH * GROWS * 2 + fixed > ws_size) tchunk >>= 1;

  char* p = (char*)d_ws;
  uint16_t* xp   = (uint16_t*)p;  p += (size_t)tchunk * BATCH * GROWS * 2;
  uint16_t* wihb = (uint16_t*)p;  p += (size_t)GROWS * KDIM * 2;
  int8_t*   wq   = (int8_t*)p;    p += (size_t)GROWS * KDIM;
  float*    wsc  = (float*)p;     p += (size_t)GROWS * 4;
  float*    cbuf = (float*)p;

  setup_kernel<<<dim3((GROWS * KDIM + 255) / 256), dim3(256), 0, stream>>>(
      Wih, c0, wihb, cbuf);
  wquant_kernel<<<dim3((GROWS + 255) / 256), dim3(256), 0, stream>>>(Whh, wq, wsc);
  for (int s0 = 0; s0 < T_LEN; s0 += tchunk) {
    xproj_kernel<<<dim3(tchunk / 2), dim3(256), 0, stream>>>(x, wihb, bias, xp, s0);
    const float* h_src = (s0 == 0) ? h0 : (seq + (size_t)(s0 - 1) * BATCH * HID);
    scan_kernel<<<dim3(NSWG), dim3(1024), 0, stream>>>(
        mIn, wq, wsc, xp, h_src, cbuf, seq, hT, cT, s0, s0 + tchunk);
  }
}

// Round 9
// 3642.625 us; speedup vs baseline: 1.8005x; 1.0993x over previous
//
#include <hip/hip_runtime.h>
#include <stdint.h>
#include <stddef.h>

#define T_LEN 1024
#define BATCH 64
#define KDIM  256
#define HID   256
#define NGATE 5
#define GROWS (NGATE * HID)   // 1280
#define NGT   (GROWS / 16)    // 80 gate tiles of 16 rows
#define NSWG  4               // scan WGs: 16 batch rows each, fully independent

typedef __attribute__((ext_vector_type(8))) short s16x8;   // 8 bf16
typedef __attribute__((ext_vector_type(4))) float f32x4;
typedef __attribute__((ext_vector_type(4))) int   i32x4;
typedef __attribute__((ext_vector_type(2))) unsigned int u32x2;

static __device__ __forceinline__ uint16_t f2bf(float f) {
  uint32_t u = __float_as_uint(f);
  return (uint16_t)((u + 0x7fffu + ((u >> 16) & 1u)) >> 16);   // RNE
}
static __device__ __forceinline__ float bf2f(uint16_t b) {
  return __uint_as_float(((uint32_t)b) << 16);
}
static __device__ __forceinline__ s16x8 cvt8(const float* __restrict__ p) {
  float4 a = *reinterpret_cast<const float4*>(p);
  float4 b = *reinterpret_cast<const float4*>(p + 4);
  union { s16x8 v; uint16_t u[8]; } r;
  r.u[0] = f2bf(a.x); r.u[1] = f2bf(a.y); r.u[2] = f2bf(a.z); r.u[3] = f2bf(a.w);
  r.u[4] = f2bf(b.x); r.u[5] = f2bf(b.y); r.u[6] = f2bf(b.z); r.u[7] = f2bf(b.w);
  return r.v;
}
// 1-instruction reciprocal (v_rcp_f32): replaces the ~9-instr fp32 div expansion.
static __device__ __forceinline__ float rcp_hw(float x) {
  float r; asm("v_rcp_f32 %0, %1" : "=v"(r) : "v"(x)); return r;
}
static __device__ __forceinline__ float sigm(float x) {        // 1/(1+e^-x)
  return rcp_hw(1.f + __expf(-x));
}
static __device__ __forceinline__ float tanh_f(float x) {      // 1 - 2/(e^2x+1)
  return __builtin_fmaf(-2.f, rcp_hw(1.f + __expf(2.f * x)), 1.f);
}
// LDS swizzle for hq: XOR 16B-block index with row (breaks stride-256B bank collision)
static __device__ __forceinline__ int swz(int row, int col) {
  return ((((col >> 4) ^ (row & 15)) << 4) | (col & 15));
}

// MFMA via inline asm: acc and (for resident gates) B pinned to AGPRs — gfx950 MFMA
// reads AGPR operands directly, so weights never shuffle through arch VGPRs.
#define MFMA_AW(acc, A, W) \
  asm("v_mfma_i32_16x16x64_i8 %0, %1, %2, %0" : "+a"(acc) : "v"(A), "a"(W))
#define MFMA_AV(acc, A, B) \
  asm("v_mfma_i32_16x16x64_i8 %0, %1, %2, %0" : "+a"(acc) : "v"(A), "v"(B))

// ---------------- setup: W_ih -> bf16, c0 -> cbuf ----------------
__global__ void setup_kernel(const float* __restrict__ Wih, const float* __restrict__ c0,
                             uint16_t* __restrict__ wihb, float* __restrict__ cbuf) {
  int i = blockIdx.x * 256 + threadIdx.x;
  if (i < GROWS * KDIM) wihb[i] = f2bf(Wih[i]);
  if (i < BATCH * HID) cbuf[i] = c0[i];
}

// ---------------- W_hh -> int8 per-row quant ----------------
__global__ void wquant_kernel(const float* __restrict__ Whh,
                              int8_t* __restrict__ wq, float* __restrict__ wsc) {
  int row = blockIdx.x * 256 + threadIdx.x;
  if (row >= GROWS) return;
  const float* wr = Whh + (size_t)row * KDIM;
  float mx = 1e-30f;
  for (int k = 0; k < KDIM; ++k) mx = fmaxf(mx, fabsf(wr[k]));
  wsc[row] = mx / 127.f;
  const float inv = 127.f / mx;
  int8_t* q = wq + (size_t)row * KDIM;
  for (int k = 0; k < KDIM; ++k) q[k] = (int8_t)__float2int_rn(wr[k] * inv);
}

// ---------------- x projection (bf16 MFMA, per-lane C-fragment layout) ----------------
__global__ __launch_bounds__(256, 2)
void xproj_kernel(const float* __restrict__ x, const uint16_t* __restrict__ wihb,
                  const float* __restrict__ bias, uint16_t* __restrict__ xp, int t0) {
  const int w = threadIdx.x >> 6, lane = threadIdx.x & 63;
  const int r16 = lane & 15, ke = (lane >> 4) * 8;
  const int tA = t0 + (int)blockIdx.x * 2;

  s16x8 A[2][8];
#pragma unroll
  for (int tt = 0; tt < 2; ++tt) {
    const float* ap = x + ((size_t)(tA + tt) * BATCH + w * 16 + r16) * KDIM + ke;
#pragma unroll
    for (int ks = 0; ks < 8; ++ks) A[tt][ks] = cvt8(ap + ks * 32);
  }
  for (int gt = 0; gt < NGT; ++gt) {
    const uint16_t* bp = wihb + (size_t)(gt * 16 + r16) * KDIM + ke;
    s16x8 B[8];
#pragma unroll
    for (int ks = 0; ks < 8; ++ks) B[ks] = *reinterpret_cast<const s16x8*>(bp + ks * 32);
    const float bv = bias[gt * 16 + r16];
#pragma unroll
    for (int tt = 0; tt < 2; ++tt) {
      f32x4 acc = {};
#pragma unroll
      for (int ks = 0; ks < 8; ++ks)
        acc = __builtin_amdgcn_mfma_f32_16x16x32_bf16(A[tt][ks], B[ks], acc, 0, 0, 0);
      const int lt = (int)blockIdx.x * 2 + tt;
      uint32_t w0 = (uint32_t)f2bf(acc[0] + bv) | ((uint32_t)f2bf(acc[1] + bv) << 16);
      uint32_t w1 = (uint32_t)f2bf(acc[2] + bv) | ((uint32_t)f2bf(acc[3] + bv) << 16);
      u32x2 pk = {w0, w1};
      u32x2* dst = (u32x2*)((uint32_t*)(xp + ((size_t)(lt * 4 + w) * NGT + gt) * 256) + lane * 2);
      __builtin_nontemporal_store(pk, dst);
    }
  }
}

// ---------------- sequential scan: 4 independent WGs, 16 waves each ----------------
// WG owns 16 batch rows; wave v owns H-cols [v*16, v*16+16), all 5 gates.
// Weights i8: gates {i,f,g} AGPR-resident ("a" asm operands, 48 AGPRs); gates {o,r}
// in LDS fragments. Accumulators in AGPRs. Arch-VGPR working set ~60 fits the
// allocator's 64-reg point by design. h via LDS i8 double buffer + one raw
// s_barrier/step; xp/m prefetched one step ahead; v_rcp_f32 gate math.
__global__ __launch_bounds__(1024, 4)
void scan_kernel(const float* __restrict__ mIn, const int8_t* __restrict__ wq,
                 const float* __restrict__ wsc, const uint16_t* __restrict__ xp,
                 const float* __restrict__ h_src, float* __restrict__ cbuf,
                 float* __restrict__ seq, float* __restrict__ hT, float* __restrict__ cT,
                 int s0, int s1) {
  struct SW {
    int8_t w[16][2][4][1024];   // [wave][ldsgate][ks][lane*16]  128 KB
    int8_t hq[2][16][256];      // h double buffer, swizzled       8 KB
  };
  __shared__ SW sl;
  const int wg = blockIdx.x;                // batch tile (16 rows)
  const int v = threadIdx.x >> 6;           // wave 0..15 = H col-block
  const int lane = threadIdx.x & 63;
  const int r16 = lane & 15, g4 = lane >> 4;
  const int bj0 = g4 * 4;                   // batch row (within tile) base, C layout
  const int brow = wg * 16;                 // global batch base
  const int col = v * 16 + r16;             // owned H column

  // AGPR-resident gates 0..2 + all scales
  i32x4 Wf0[4], Wf1[4], Wf2[4];
  float sc[NGATE];
#pragma unroll
  for (int g = 0; g < NGATE; ++g) sc[g] = wsc[g * 256 + col] * (1.f / 127.f);
  {
    const int8_t* wp0 = wq + (size_t)(0 * 256 + col) * KDIM + g4 * 16;
    const int8_t* wp1 = wq + (size_t)(1 * 256 + col) * KDIM + g4 * 16;
    const int8_t* wp2 = wq + (size_t)(2 * 256 + col) * KDIM + g4 * 16;
#pragma unroll
    for (int ks = 0; ks < 4; ++ks) {
      Wf0[ks] = *reinterpret_cast<const i32x4*>(wp0 + ks * 64);
      Wf1[ks] = *reinterpret_cast<const i32x4*>(wp1 + ks * 64);
      Wf2[ks] = *reinterpret_cast<const i32x4*>(wp2 + ks * 64);
    }
  }
  // LDS-resident gates 3,4: each wave writes its own fragments in per-lane order
#pragma unroll
  for (int gl = 0; gl < 2; ++gl) {
    const int grow = (3 + gl) * 256 + col;
    const int8_t* wp = wq + (size_t)grow * KDIM + g4 * 16;
#pragma unroll
    for (int ks = 0; ks < 4; ++ks)
      *reinterpret_cast<i32x4*>(&sl.w[v][gl][ks][lane * 16]) =
          *reinterpret_cast<const i32x4*>(wp + ks * 64);
  }

  float c[4];
#pragma unroll
  for (int j = 0; j < 4; ++j)
    c[j] = cbuf[(size_t)(brow + bj0 + j) * HID + col];

  // entry h (h0 or seq[s0-1]) -> quantized into LDS buf parity s0&1
  {
    const int p0 = s0 & 1;
#pragma unroll
    for (int e = 0; e < 4; ++e) {
      int t = (int)threadIdx.x * 4 + e;
      int row = t >> 8, cc = t & 255;
      float hv = h_src[(size_t)(brow + row) * HID + cc];
      int q = __float2int_rn(fminf(fmaxf(hv * 127.f, -127.f), 127.f));
      sl.hq[p0][row][swz(row, cc)] = (int8_t)q;
    }
  }
  __syncthreads();

  // hoisted swizzled LDS byte offsets (within a 4 KB hq buffer)
  int aoff[4], woff[4];
#pragma unroll
  for (int ks = 0; ks < 4; ++ks) aoff[ks] = r16 * 256 + swz(r16, (g4 + 4 * ks) * 16);
#pragma unroll
  for (int j = 0; j < 4; ++j) woff[j] = (bj0 + j) * 256 + swz(bj0 + j, col);

  // stepping pointers
  const uint16_t* xpb = xp + ((size_t)wg * NGT + v) * 256 + lane * 4;
  const float*    mb  = mIn + ((size_t)s0 * BATCH + brow + bj0) * HID + col;
  float*          sqb = seq + ((size_t)s0 * BATCH + brow + bj0) * HID + col;

  // prologue prefetch for step s0
  u32x2 xpf[NGATE];
  float mv[4];
#pragma unroll
  for (int g = 0; g < NGATE; ++g)
    xpf[g] = *reinterpret_cast<const u32x2*>(xpb + g * 16 * 256);
#pragma unroll
  for (int j = 0; j < 4; ++j) mv[j] = mb[j * HID];

  int8_t* const hq0 = &sl.hq[0][0][0];

  for (int s = s0; s < s1; ++s) {
    const int p = s & 1;
    const int8_t* hr = hq0 + p * 4096;        // read buffer
    int8_t*       hw = hq0 + (p ^ 1) * 4096;  // write buffer

    // MFMA phase: A from hq; gates 0-2 weights from AGPR, gates 3-4 from LDS
    i32x4 acc[NGATE];
#pragma unroll
    for (int g = 0; g < NGATE; ++g) acc[g] = i32x4{0, 0, 0, 0};
    __builtin_amdgcn_s_setprio(1);
#pragma unroll
    for (int ks = 0; ks < 4; ++ks) {
      i32x4 A = *reinterpret_cast<const i32x4*>(hr + aoff[ks]);
      MFMA_AW(acc[0], A, Wf0[ks]);
      MFMA_AW(acc[1], A, Wf1[ks]);
      MFMA_AW(acc[2], A, Wf2[ks]);
      i32x4 b0 = *reinterpret_cast<const i32x4*>(&sl.w[v][0][ks][lane * 16]);
      MFMA_AV(acc[3], A, b0);
      i32x4 b1 = *reinterpret_cast<const i32x4*>(&sl.w[v][1][ks][lane * 16]);
      MFMA_AV(acc[4], A, b1);
    }
    __builtin_amdgcn_s_setprio(0);

    // gate math (consumes xpf/mv prefetched one step ago)
    float hnew[4];
#pragma unroll
    for (int j = 0; j < 4; ++j) {
#define XPV(g) bf2f((uint16_t)((j & 1) ? (xpf[g][j >> 1] >> 16) : (xpf[g][j >> 1] & 0xffff)))
      const float gi = __builtin_fmaf((float)acc[0][j], sc[0], XPV(0));
      const float gf = __builtin_fmaf((float)acc[1][j], sc[1], XPV(1));
      const float gg = __builtin_fmaf((float)acc[2][j], sc[2], XPV(2));
      const float go = __builtin_fmaf((float)acc[3][j], sc[3], XPV(3));
      const float gr = __builtin_fmaf((float)acc[4][j], sc[4], XPV(4));
#undef XPV
      const float cn = sigm(gf) * c[j] + sigm(gi) * tanh_f(gg) + sigm(gr) * mv[j];
      c[j] = cn;
      hnew[j] = sigm(go) * tanh_f(cn);
    }

    // prefetch next step into the (now free) xpf/mv regs — overlaps barrier + next MFMA
    const uint16_t* xpb_n = xpb + 4 * NGT * 256;                 // beyond-chunk read stays in ws
    const float*    mb_n  = (s + 1 < s1) ? mb + BATCH * HID : mb;
#pragma unroll
    for (int g = 0; g < NGATE; ++g)
      xpf[g] = *reinterpret_cast<const u32x2*>(xpb_n + g * 16 * 256);
#pragma unroll
    for (int j = 0; j < 4; ++j) mv[j] = mb_n[j * HID];
    xpb = xpb_n; mb = mb_n;

    // outputs + quantized h into next LDS buffer
#pragma unroll
    for (int j = 0; j < 4; ++j) {
      __builtin_nontemporal_store(hnew[j], sqb + j * HID);
      int q = __float2int_rn(hnew[j] * 127.f);
      hw[woff[j]] = (int8_t)q;
    }
    if (s == T_LEN - 1) {
#pragma unroll
      for (int j = 0; j < 4; ++j) {
        hT[(size_t)(brow + bj0 + j) * HID + col] = hnew[j];
        cT[(size_t)(brow + bj0 + j) * HID + col] = c[j];
      }
    }
    sqb += BATCH * HID;

    // raw barrier: only LDS ordering needed (global loads/stores keep flying)
    __builtin_amdgcn_sched_barrier(0);
    asm volatile("s_waitcnt lgkmcnt(0)" ::: "memory");
    __builtin_amdgcn_s_barrier();
    __builtin_amdgcn_sched_barrier(0);
  }

  // persist c for next chunk
#pragma unroll
  for (int j = 0; j < 4; ++j)
    cbuf[(size_t)(brow + bj0 + j) * HID + col] = c[j];
}

extern "C" void kernel_launch(void* const* d_in, const int* in_sizes, int n_in,
                              void* d_out, int out_size, void* d_ws, size_t ws_size,
                              hipStream_t stream) {
  (void)in_sizes; (void)n_in; (void)out_size;
  const float* x    = (const float*)d_in[0];
  const float* mIn  = (const float*)d_in[1];
  const float* h0   = (const float*)d_in[2];
  const float* c0   = (const float*)d_in[3];
  const float* Wih  = (const float*)d_in[4];
  const float* Whh  = (const float*)d_in[5];
  const float* bias = (const float*)d_in[6];
  float* out = (float*)d_out;
  float* seq = out;
  float* hT  = out + (size_t)T_LEN * BATCH * HID;
  float* cT  = hT + (size_t)BATCH * HID;

  const size_t fixed = (size_t)GROWS * KDIM * 2 + (size_t)GROWS * KDIM
                     + (size_t)GROWS * 4 + (size_t)BATCH * HID * 4 + 4096;
  int tchunk = T_LEN;
  while (tchunk > 2 && (size_t)tchunk * BATCH * GROWS * 2 + fixed > ws_size) tchunk >>= 1;

  char* p = (char*)d_ws;
  uint16_t* xp   = (uint16_t*)p;  p += (size_t)tchunk * BATCH * GROWS * 2;
  uint16_t* wihb = (uint16_t*)p;  p += (size_t)GROWS * KDIM * 2;
  int8_t*   wq   = (int8_t*)p;    p += (size_t)GROWS * KDIM;
  float*    wsc  = (float*)p;     p += (size_t)GROWS * 4;
  float*    cbuf = (float*)p;

  setup_kernel<<<dim3((GROWS * KDIM + 255) / 256), dim3(256), 0, stream>>>(
      Wih, c0, wihb, cbuf);
  wquant_kernel<<<dim3((GROWS + 255) / 256), dim3(256), 0, stream>>>(Whh, wq, wsc);
  for (int s0 = 0; s0 < T_LEN; s0 += tchunk) {
    xproj_kernel<<<dim3(tchunk / 2), dim3(256), 0, stream>>>(x, wihb, bias, xp, s0);
    const float* h_src = (s0 == 0) ? h0 : (seq + (size_t)(s0 - 1) * BATCH * HID);
    scan_kernel<<<dim3(NSWG), dim3(1024), 0, stream>>>(
        mIn, wq, wsc, xp, h_src, cbuf, seq, hT, cT, s0, s0 + tchunk);
  }
}